// Round 18
// baseline (532.242 us; speedup 1.0000x reference)
//
#include <hip/hip_runtime.h>
#include <hip/hip_bf16.h>
#include <math.h>

#define NN 100000
#define NE 1600000
#define NEP 1700000        // NE + NN (self loops)
#define HD 64
#define NEGS 0.2f

typedef float f2 __attribute__((ext_vector_type(2)));
typedef float f4 __attribute__((ext_vector_type(4)));

__device__ __forceinline__ f2 sp2(float v) { return (f2){v, v}; }
__device__ __forceinline__ f4 sp4(float v) { return (f4){v, v, v, v}; }
__device__ __forceinline__ f2 ffma2(f2 a, f2 b, f2 c) {
#if __has_builtin(__builtin_elementwise_fma)
  return __builtin_elementwise_fma(a, b, c);
#else
  return a * b + c;
#endif
}
__device__ __forceinline__ f4 ffma4(f4 a, f4 b, f4 c) {
#if __has_builtin(__builtin_elementwise_fma)
  return __builtin_elementwise_fma(a, b, c);
#else
  return a * b + c;
#endif
}
__device__ __forceinline__ f2 fmax2(f2 a, f2 b) {
#if __has_builtin(__builtin_elementwise_max)
  return __builtin_elementwise_max(a, b);
#else
  f2 r; r.x = fmaxf(a.x, b.x); r.y = fmaxf(a.y, b.y); return r;
#endif
}
__device__ __forceinline__ f4 fmax4(f4 a, f4 b) {
#if __has_builtin(__builtin_elementwise_max)
  return __builtin_elementwise_max(a, b);
#else
  f4 r; r.x = fmaxf(a.x, b.x); r.y = fmaxf(a.y, b.y);
  r.z = fmaxf(a.z, b.z); r.w = fmaxf(a.w, b.w); return r;
#endif
}
// guaranteed v_readlane broadcast (never ds_bpermute); lane may be a
// runtime-uniform value, so partial unroll is safe (R11/R15 lesson).
__device__ __forceinline__ float rdlane(float v, int lane) {
  return __int_as_float(__builtin_amdgcn_readlane(__float_as_int(v), lane));
}

// ============================ CSR build ============================

__global__ void k_init_cnt(int* __restrict__ cnt, int* __restrict__ hist,
                           int* __restrict__ cursor2) {
  int i = blockIdx.x * 256 + threadIdx.x;
  if (i < NN) cnt[i] = 1;             // self loop pre-counted -> ranks start at 1
  if (blockIdx.x == 0) {
    if (threadIdx.x < 64) hist[threadIdx.x] = 0;
    else if (threadIdx.x < 128) cursor2[threadIdx.x - 64] = 0;
  }
}

// count in-degree AND record each edge's (temporary, nondeterministic) rank.
// rank >= 1; slot rp[dst]+0 is reserved for the self loop. The rank is only
// used for PLACEMENT; k_sortscat canonicalizes segment order afterwards.
__global__ void k_count_rank(const int* __restrict__ dst, int* __restrict__ cnt,
                             int* __restrict__ rank) {
  int base = (blockIdx.x * 256 + threadIdx.x) * 4;
  if (base >= NE) return;
  int4 dv = *(const int4*)(dst + base);
  int4 rv;
  rv.x = atomicAdd(&cnt[dv.x], 1);
  rv.y = atomicAdd(&cnt[dv.y], 1);
  rv.z = atomicAdd(&cnt[dv.z], 1);
  rv.w = atomicAdd(&cnt[dv.w], 1);
  *(int4*)(rank + base) = rv;
}

// scan of cnt -> rp (exclusive) ; also 64-bin degree histogram (LDS-batched)
__global__ void k_scan_a(const int* __restrict__ cnt, int* __restrict__ rp,
                         int* __restrict__ bsum, int* __restrict__ hist) {
  __shared__ int tmp[1024];
  __shared__ int lh[64];
  int t = threadIdx.x, b = blockIdx.x;
  int i = b * 1024 + t;
  int v = (i < NN) ? cnt[i] : 0;
  tmp[t] = v;
  if (t < 64) lh[t] = 0;
  __syncthreads();
  if (i < NN) atomicAdd(&lh[v < 63 ? v : 63], 1);
  for (int off = 1; off < 1024; off <<= 1) {
    int a = (t >= off) ? tmp[t - off] : 0;
    __syncthreads(); tmp[t] += a; __syncthreads();
  }
  if (i < NN) rp[i] = tmp[t] - v;     // exclusive
  if (t == 1023) bsum[b] = tmp[t];    // block total
  if (t < 64) { int h = lh[t]; if (h) atomicAdd(&hist[t], h); }
}

__global__ void k_scan_b(const int* __restrict__ bsum, int* __restrict__ boff, int nb,
                         const int* __restrict__ hist, int* __restrict__ cursor2) {
  __shared__ int tmp[1024];
  int t = threadIdx.x;
  int v = (t < nb) ? bsum[t] : 0;
  tmp[t] = v; __syncthreads();
  for (int off = 1; off < 1024; off <<= 1) {
    int a = (t >= off) ? tmp[t - off] : 0;
    __syncthreads(); tmp[t] += a; __syncthreads();
  }
  if (t < nb) boff[t] = tmp[t] - v;
  // exclusive scan of 64-bin degree histogram (wave 0 only) -> bin bases
  if (t < 64) {
    int h = hist[t];
    int s = h;
#pragma unroll
    for (int off = 1; off < 64; off <<= 1) {
      int u = __shfl_up(s, off);
      if (t >= off) s += u;
    }
    cursor2[t] = s - h;
  }
}

// finalize rp and scatter nodes into degree-bucketed order[].
// Hierarchical rank: LDS histogram -> one global atomic per (block,bin).
// order[] is a nondeterministic permutation WITHIN degree bins, but it only
// controls which nodes share a wave in k_fused — no node's math depends on it.
__global__ void k_scan_c(int* __restrict__ rp, const int* __restrict__ boff,
                         const int* __restrict__ deg,   // aliases cnt (degree)
                         int* __restrict__ cursor2, int* __restrict__ order) {
  __shared__ int lh[64];
  __shared__ int lbase[64];
  int t = threadIdx.x, b = blockIdx.x;
  int i = b * 1024 + t;
  if (t < 64) lh[t] = 0;
  __syncthreads();
  int bin = 0, lr = 0;
  if (i < NN) {
    int d = deg[i];
    bin = d < 63 ? d : 63;
    lr = atomicAdd(&lh[bin], 1);       // local rank within (block, bin)
    rp[i] = rp[i] + boff[b];
  }
  __syncthreads();
  if (t < 64) {
    int h = lh[t];
    lbase[t] = h ? atomicAdd(&cursor2[t], h) : 0;   // reserve range
  }
  __syncthreads();
  if (i < NN) order[lbase[bin] + lr] = i;
  if (i == 0) rp[NN] = NEP;
}

// ============ scatter edge IDs into segment slots (4B stores) ============
__global__ void __launch_bounds__(256) k_scatter_id(
    const int* __restrict__ dst, const int* __restrict__ rank,
    const int* __restrict__ rp, int* __restrict__ eid) {
  int base = (blockIdx.x * 256 + threadIdx.x) * 4;
  if (base >= NE) return;
  int4 dv = *(const int4*)(dst + base);
  int4 rv = *(const int4*)(rank + base);
  eid[rp[dv.x] + rv.x] = base + 0;
  eid[rp[dv.y] + rv.y] = base + 1;
  eid[rp[dv.z] + rv.z] = base + 2;
  eid[rp[dv.w] + rv.w] = base + 3;
}

// == canonicalize segment order (bitonic sort) + build records + self mean ==
// Wave per node: sort the <=64 edge ids ascending, gather src/ea, write the
// 32B records (coalesced), then butterfly-sum the attrs across the wave and
// lane 0 writes the self-loop mean record at slot rp[n]. All content is a
// deterministic function of inputs -> bitwise-identical output every call.
__global__ void __launch_bounds__(256) k_sortscat(
    const int* __restrict__ rp, int* __restrict__ eid,
    const int* __restrict__ src, const float* __restrict__ ea,
    float* __restrict__ rec) {
  int tid = threadIdx.x;
  int lane = tid & 63, wid = tid >> 6;
  int n = blockIdx.x * 4 + wid;
  if (n >= NN) return;
  int p0 = rp[n], p1 = rp[n + 1];
  int len = p1 - p0 - 1;               // number of real edges (slot p0 = self)
  if (len <= 0) {                      // isolated node: zero self record
    if (lane == 0) {
      float* r = rec + (size_t)p0 * 8;
      *(f4*)r       = (f4){__int_as_float(n), 0.f, 0.f, 0.f};
      *(f4*)(r + 4) = (f4){0.f, 0.f, 0.f, 0.f};
    }
    return;
  }
  f2 e01 = (f2){0, 0}, e23 = (f2){0, 0}, e45 = (f2){0, 0};
  if (len <= 64) {
    int v = (lane < len) ? eid[p0 + 1 + lane] : 0x7fffffff;
#pragma unroll
    for (int k = 2; k <= 64; k <<= 1) {
#pragma unroll
      for (int j = k >> 1; j > 0; j >>= 1) {
        int u = __shfl_xor(v, j);
        bool up = ((lane & k) == 0);
        bool lower = ((lane & j) == 0);
        int mn = v < u ? v : u;
        int mx = v < u ? u : v;
        v = (up == lower) ? mn : mx;
      }
    }
    if (lane < len) {
      int id = v;
      e01 = *(const f2*)(ea + (size_t)id * 6);
      e23 = *(const f2*)(ea + (size_t)id * 6 + 2);
      e45 = *(const f2*)(ea + (size_t)id * 6 + 4);
      int s = src[id];
      float* r = rec + (size_t)(p0 + 1 + lane) * 8;
      *(f4*)r       = (f4){__int_as_float(s), e01.x, e01.y, e23.x};
      *(f4*)(r + 4) = (f4){e23.y, e45.x, e45.y, 0.f};
    }
    // wave butterfly sum (idle lanes contribute 0) -> self-loop mean
    float s0 = e01.x, s1 = e01.y, s2 = e23.x, s3 = e23.y, s4 = e45.x, s5 = e45.y;
#pragma unroll
    for (int off = 1; off < 64; off <<= 1) {
      s0 += __shfl_xor(s0, off); s1 += __shfl_xor(s1, off);
      s2 += __shfl_xor(s2, off); s3 += __shfl_xor(s3, off);
      s4 += __shfl_xor(s4, off); s5 += __shfl_xor(s5, off);
    }
    if (lane == 0) {
      float inv = 1.0f / (float)len;
      float* r = rec + (size_t)p0 * 8;
      *(f4*)r       = (f4){__int_as_float(n), s0 * inv, s1 * inv, s2 * inv};
      *(f4*)(r + 4) = (f4){s3 * inv, s4 * inv, s5 * inv, 0.f};
    }
  } else {                              // deg > 64: ~impossible, serial path
    if (lane == 0) {
      for (int a = p0 + 2; a < p1; ++a) {
        int key = eid[a], b = a - 1;
        while (b > p0 && eid[b] > key) { eid[b + 1] = eid[b]; --b; }
        eid[b + 1] = key;
      }
      float s0 = 0, s1 = 0, s2 = 0, s3 = 0, s4 = 0, s5 = 0;
      for (int p = p0 + 1; p < p1; ++p) {
        int id = eid[p];
        f2 a01 = *(const f2*)(ea + (size_t)id * 6);
        f2 a23 = *(const f2*)(ea + (size_t)id * 6 + 2);
        f2 a45 = *(const f2*)(ea + (size_t)id * 6 + 4);
        s0 += a01.x; s1 += a01.y; s2 += a23.x;
        s3 += a23.y; s4 += a45.x; s5 += a45.y;
        float* r = rec + (size_t)p * 8;
        *(f4*)r       = (f4){__int_as_float(src[id]), a01.x, a01.y, a23.x};
        *(f4*)(r + 4) = (f4){a23.y, a45.x, a45.y, 0.f};
      }
      float inv = 1.0f / (float)len;
      float* r = rec + (size_t)p0 * 8;
      *(f4*)r       = (f4){__int_as_float(n), s0 * inv, s1 * inv, s2 * inv};
      *(f4*)(r + 4) = (f4){s3 * inv, s4 * inv, s5 * inv, 0.f};
    }
  }
}

// ====================== node transforms (xl, xr) ======================
// Wave handles 8 nodes, lane = channel. Weights in LDS packed 2-k per f4;
// per k-pair one ds_read_b128 + explicit v_readlane broadcasts (never
// ds_bpermute) + v_pk_fma_f32. Partial unroll batches 4 b128 loads.
template <int DIN>
__global__ void __launch_bounds__(256) k_xform5(
    const float* __restrict__ x,
    const float* __restrict__ wl, const float* __restrict__ bl,
    const float* __restrict__ wr, const float* __restrict__ br,
    float* __restrict__ xl, float* __restrict__ xr) {
  __shared__ f4 w_s[(DIN / 2) * 64];
  int tid = threadIdx.x;
  for (int idx = tid; idx < (DIN / 2) * 64; idx += 256) {
    int kk = idx >> 6, h2 = idx & 63;
    w_s[idx] = (f4){wl[(2 * kk) * 64 + h2],     wr[(2 * kk) * 64 + h2],
                    wl[(2 * kk + 1) * 64 + h2], wr[(2 * kk + 1) * 64 + h2]};
  }
  __syncthreads();
  int lane = tid & 63, wid = tid >> 6;
  int h = lane;
  f2 bpk = (f2){bl[h], br[h]};
  int n0 = (blockIdx.x * 4 + wid) * 8;       // 8 nodes per wave, exact fit
  float xv[8];
#pragma unroll
  for (int j = 0; j < 8; ++j)
    xv[j] = (lane < DIN) ? x[(size_t)(n0 + j) * DIN + lane] : 0.0f;
  f2 acc[8];
#pragma unroll
  for (int j = 0; j < 8; ++j) acc[j] = bpk;
#pragma unroll 4
  for (int kk = 0; kk < DIN / 2; ++kk) {
    f4 w = w_s[kk * 64 + h];
    f2 w0 = (f2){w.x, w.y};
    f2 w1 = (f2){w.z, w.w};
#pragma unroll
    for (int j = 0; j < 8; ++j) {
      float xk0 = rdlane(xv[j], 2 * kk);
      float xk1 = rdlane(xv[j], 2 * kk + 1);
      acc[j] = ffma2(sp2(xk0), w0, acc[j]);
      acc[j] = ffma2(sp2(xk1), w1, acc[j]);
    }
  }
#pragma unroll
  for (int j = 0; j < 8; ++j) {
    xl[(size_t)(n0 + j) * 64 + h] = acc[j].x;
    xr[(size_t)(n0 + j) * 64 + h] = acc[j].y;
  }
}

// ============== fused edge-logit + online softmax + aggregate ==============
// 16 lanes per node, 4 channels per lane, 4 node-groups per wave, LPT node
// assignment. 2-edge pairs, SOFTWARE-PIPELINED one iteration deep: the next
// pair's rec records load into rotating registers while the current pair's
// xl gathers + math run — removes the rec leg (~200cy) from the per-
// iteration dependence chain (the R17 within-iteration unroll did not).
__global__ void __launch_bounds__(256) k_fused(
    const float* __restrict__ xl, const float* __restrict__ xr,
    const float* __restrict__ rec,
    const int* __restrict__ rp, const int* __restrict__ order,
    const float* __restrict__ we, const float* __restrict__ att,
    const float* __restrict__ bo, float* __restrict__ hout) {
  int tid = threadIdx.x;
  int lane = tid & 63;
  int q = lane & 15;
  int ch0 = q * 4;
  f2 w0a, w0b, w1a, w1b, w2a, w2b, w3a, w3b, w4a, w4b, w5a, w5b;
  w0a = *(const f2*)(we + 0 * 64 + ch0); w0b = *(const f2*)(we + 0 * 64 + ch0 + 2);
  w1a = *(const f2*)(we + 1 * 64 + ch0); w1b = *(const f2*)(we + 1 * 64 + ch0 + 2);
  w2a = *(const f2*)(we + 2 * 64 + ch0); w2b = *(const f2*)(we + 2 * 64 + ch0 + 2);
  w3a = *(const f2*)(we + 3 * 64 + ch0); w3b = *(const f2*)(we + 3 * 64 + ch0 + 2);
  w4a = *(const f2*)(we + 4 * 64 + ch0); w4b = *(const f2*)(we + 4 * 64 + ch0 + 2);
  w5a = *(const f2*)(we + 5 * 64 + ch0); w5b = *(const f2*)(we + 5 * 64 + ch0 + 2);
  f2 ata = *(const f2*)(att + ch0) * 1.44269504f;      // fold log2(e)
  f2 atb = *(const f2*)(att + ch0 + 2) * 1.44269504f;
  f2 boa = *(const f2*)(bo + ch0);
  f2 bob = *(const f2*)(bo + ch0 + 2);
  int gw = (blockIdx.x * 256 + tid) >> 6;       // global wave id
  int slot = gw * 4 + (lane >> 4);              // node slot for this group
  int n = (slot < NN) ? order[NN - 1 - slot] : -1;   // LPT: heavy first
  int p0 = 0, p1 = 0;
  f2 xra = (f2){0, 0}, xrb2 = (f2){0, 0};
  if (n >= 0) {
    p0 = rp[n]; p1 = rp[n + 1];
    const f4 t = *(const f4*)(xr + (size_t)n * 64 + ch0);
    xra = (f2){t.x, t.y}; xrb2 = (f2){t.z, t.w};
  }
  // per-edge lane-local logit partial (pre-butterfly)
  auto elogit = [&](f4 r0, f4 r1, f2 xa, f2 xb) -> float {
    f2 t = xa + xra;
    t = ffma2(sp2(r0.y), w0a, t); t = ffma2(sp2(r0.z), w1a, t);
    t = ffma2(sp2(r0.w), w2a, t); t = ffma2(sp2(r1.x), w3a, t);
    t = ffma2(sp2(r1.y), w4a, t); t = ffma2(sp2(r1.z), w5a, t);
    f2 pv = fmax2(t, sp2(0.2f) * t) * ata;
    f2 u = xb + xrb2;
    u = ffma2(sp2(r0.y), w0b, u); u = ffma2(sp2(r0.z), w1b, u);
    u = ffma2(sp2(r0.w), w2b, u); u = ffma2(sp2(r1.x), w3b, u);
    u = ffma2(sp2(r1.y), w4b, u); u = ffma2(sp2(r1.z), w5b, u);
    pv = ffma2(fmax2(u, sp2(0.2f) * u), atb, pv);
    return pv.x + pv.y;
  };
  float m = -INFINITY, den = 0.0f;
  f2 acca = (f2){0, 0}, accb = (f2){0, 0};
  int npair = (p1 - p0) >> 1;
  int p = p0;
  f4 cA0, cA1, cB0, cB1;                     // current pair rec (rotating)
  if (npair > 0) {
    const f4* ra = (const f4*)(rec + (size_t)p * 8);
    cA0 = ra[0]; cA1 = ra[1]; cB0 = ra[2]; cB1 = ra[3];
  }
  for (int it = 0; it < npair; ++it) {
    f4 nA0, nA1, nB0, nB1;
    if (it + 1 < npair) {                    // prefetch next pair's rec
      const f4* rb = (const f4*)(rec + (size_t)(p + 2) * 8);
      nA0 = rb[0]; nA1 = rb[1]; nB0 = rb[2]; nB1 = rb[3];
    }
    int sA = __float_as_int(cA0.x), sB = __float_as_int(cB0.x);
    f4 xA = *(const f4*)(xl + (size_t)sA * 64 + ch0);
    f4 xB = *(const f4*)(xl + (size_t)sB * 64 + ch0);
    f2 xAa = (f2){xA.x, xA.y}, xAb = (f2){xA.z, xA.w};
    f2 xBa = (f2){xB.x, xB.y}, xBb = (f2){xB.z, xB.w};
    float pa = elogit(cA0, cA1, xAa, xAb);
    float pb = elogit(cB0, cB1, xBa, xBb);
    pa += __shfl_xor(pa, 1); pb += __shfl_xor(pb, 1);
    pa += __shfl_xor(pa, 2); pb += __shfl_xor(pb, 2);
    pa += __shfl_xor(pa, 4); pb += __shfl_xor(pb, 4);
    pa += __shfl_xor(pa, 8); pb += __shfl_xor(pb, 8);
    float nm = fmaxf(m, fmaxf(pa, pb));
    float sc = exp2f(m - nm);                // first iter: exp2(-inf)=0
    float eA = exp2f(pa - nm);
    float eB = exp2f(pb - nm);
    m = nm;
    den = fmaf(den, sc, eA + eB);
    acca = ffma2(acca, sp2(sc), ffma2(sp2(eA), xAa, sp2(eB) * xBa));
    accb = ffma2(accb, sp2(sc), ffma2(sp2(eA), xAb, sp2(eB) * xBb));
    cA0 = nA0; cA1 = nA1; cB0 = nB0; cB1 = nB1;   // rotate
    p += 2;
  }
  if (p < p1) {                                  // 1-edge tail
    const f4* ra = (const f4*)(rec + (size_t)p * 8);
    f4 r0 = ra[0], r1 = ra[1];
    int s = __float_as_int(r0.x);
    f4 xt = *(const f4*)(xl + (size_t)s * 64 + ch0);
    f2 xa = (f2){xt.x, xt.y}, xb = (f2){xt.z, xt.w};
    float part = elogit(r0, r1, xa, xb);
    part += __shfl_xor(part, 1);
    part += __shfl_xor(part, 2);
    part += __shfl_xor(part, 4);
    part += __shfl_xor(part, 8);
    float nm = fmaxf(m, part);
    float sc = exp2f(m - nm);
    float ex = exp2f(part - nm);
    m = nm;
    den = fmaf(den, sc, ex);
    acca = ffma2(acca, sp2(sc), sp2(ex) * xa);
    accb = ffma2(accb, sp2(sc), sp2(ex) * xb);
  }
  if (n >= 0) {
    float inv = 1.0f / (den + 1e-16f);
    f2 oa = ffma2(acca, sp2(inv), boa);
    f2 ob = ffma2(accb, sp2(inv), bob);
    oa = fmax2(oa, (f2){0, 0});
    ob = fmax2(ob, (f2){0, 0});
    f4 o = (f4){oa.x, oa.y, ob.x, ob.y};
    *(f4*)(hout + (size_t)n * 64 + ch0) = o;
  }
}

// ====================== MLP head: 64 -> 32 (relu) -> 4 ======================
// Thread-per-node; weights broadcast from LDS; 8 independent f4 acc chains.
__global__ void __launch_bounds__(256) k_mlp2(
    const float* __restrict__ hin,
    const float* __restrict__ wlin, const float* __restrict__ blin,
    const float* __restrict__ wout, const float* __restrict__ bout,
    float* __restrict__ out) {
  __shared__ float wl_s[64 * 32];
  __shared__ float bl_s[32];
  __shared__ float wo_s[32 * 4];
  __shared__ float bo_s[4];
  int tid = threadIdx.x;
#pragma unroll
  for (int i = 0; i < 8; ++i) wl_s[tid + i * 256] = wlin[tid + i * 256];
  if (tid < 128) wo_s[tid] = wout[tid];
  if (tid < 32) bl_s[tid] = blin[tid];
  if (tid >= 32 && tid < 36) bo_s[tid - 32] = bout[tid - 32];
  __syncthreads();
  int n = blockIdx.x * 256 + tid;
  if (n >= NN) return;
  const f4* hp = (const f4*)(hin + (size_t)n * 64);
  f4 h[16];
#pragma unroll
  for (int i = 0; i < 16; ++i) h[i] = hp[i];
  f4 acc[8];
#pragma unroll
  for (int j4 = 0; j4 < 8; ++j4) acc[j4] = *(const f4*)(bl_s + j4 * 4);
#pragma unroll
  for (int k = 0; k < 64; ++k) {
    float hk = ((const float*)h)[k];
    const f4* wrow = (const f4*)(wl_s + k * 32);
#pragma unroll
    for (int j4 = 0; j4 < 8; ++j4)
      acc[j4] = ffma4(sp4(hk), wrow[j4], acc[j4]);
  }
  f4 o4 = *(const f4*)(bo_s);
#pragma unroll
  for (int j4 = 0; j4 < 8; ++j4) {
    f4 hid = fmax4(acc[j4], sp4(0.0f));
    const f4* wo = (const f4*)(wo_s + j4 * 16);
    o4 = ffma4(sp4(hid.x), wo[0], o4);
    o4 = ffma4(sp4(hid.y), wo[1], o4);
    o4 = ffma4(sp4(hid.z), wo[2], o4);
    o4 = ffma4(sp4(hid.w), wo[3], o4);
  }
  *(f4*)(out + (size_t)n * 4) = o4;
}

// ============================ launch ============================

extern "C" void kernel_launch(void* const* d_in, const int* in_sizes, int n_in,
                              void* d_out, int out_size, void* d_ws, size_t ws_size,
                              hipStream_t stream) {
  const float* x  = (const float*)d_in[0];
  const int*   ei = (const int*)d_in[1];
  const float* ea = (const float*)d_in[2];
  const int* src = ei;
  const int* dst = ei + NE;

  const float *wl[3], *bl[3], *wrm[3], *br[3], *wem[3], *attv[3], *bov[3];
  for (int l = 0; l < 3; ++l) {
    int b = 3 + l * 7;
    wl[l]  = (const float*)d_in[b + 0];
    bl[l]  = (const float*)d_in[b + 1];
    wrm[l] = (const float*)d_in[b + 2];
    br[l]  = (const float*)d_in[b + 3];
    wem[l] = (const float*)d_in[b + 4];
    attv[l]= (const float*)d_in[b + 5];
    bov[l] = (const float*)d_in[b + 6];
  }
  const float* wlin = (const float*)d_in[24];
  const float* blin = (const float*)d_in[25];
  const float* wout = (const float*)d_in[26];
  const float* bout = (const float*)d_in[27];
  float* outp = (float*)d_out;

  // workspace carve (256B aligned)
  char* w = (char*)d_ws;
  size_t off = 0;
  auto carve = [&](size_t bytes) -> void* {
    void* p = w + off;
    off += (bytes + 255) & ~(size_t)255;
    return p;
  };
  int*   cnt  = (int*)carve((size_t)NN * 4);
  int*   rp   = (int*)carve((size_t)(NN + 1) * 4);
  int*   bsum = (int*)carve(1024 * 4);
  int*   boff = (int*)carve(1024 * 4);
  int*   hist = (int*)carve(64 * 4);
  int*   cur2 = (int*)carve(64 * 4);
  int*   order= (int*)carve((size_t)NN * 4);
  int*   rank = (int*)carve((size_t)NE * 4);
  int*   eid  = (int*)carve((size_t)NEP * 4);
  float* rec  = (float*)carve((size_t)NEP * 32);      // 32B records
  float* xlb  = (float*)carve((size_t)NN * 64 * 4);
  float* xrb  = (float*)carve((size_t)NN * 64 * 4);
  float* hA   = (float*)carve((size_t)NN * 64 * 4);
  float* hB   = (float*)carve((size_t)NN * 64 * 4);
  (void)ws_size; (void)n_in; (void)in_sizes; (void)out_size;

  const int SCAN_NB = (NN + 1023) / 1024;  // 98
  const int FUSE_NB = (NN + 15) / 16;      // 6250 blocks: 4 waves x 4 groups each
  const int CR_NB   = (NE / 4 + 255) / 256;
  const int XF_NB   = NN / 32;             // 3125 blocks, 8 nodes/wave, exact
  const int SS_NB   = (NN + 3) / 4;        // sortscat: wave per node

  hipLaunchKernelGGL(k_init_cnt, dim3((NN + 255) / 256), dim3(256), 0, stream,
                     cnt, hist, cur2);
  hipLaunchKernelGGL(k_count_rank, dim3(CR_NB), dim3(256), 0, stream, dst, cnt, rank);
  hipLaunchKernelGGL(k_scan_a, dim3(SCAN_NB), dim3(1024), 0, stream, cnt, rp, bsum, hist);
  hipLaunchKernelGGL(k_scan_b, dim3(1), dim3(1024), 0, stream, bsum, boff, SCAN_NB,
                     hist, cur2);
  hipLaunchKernelGGL(k_scan_c, dim3(SCAN_NB), dim3(1024), 0, stream, rp, boff, cnt,
                     cur2, order);
  hipLaunchKernelGGL(k_scatter_id, dim3(CR_NB), dim3(256), 0, stream,
                     dst, rank, rp, eid);
  hipLaunchKernelGGL(k_sortscat, dim3(SS_NB), dim3(256), 0, stream,
                     rp, eid, src, ea, rec);

  // layer 1 (din=6): x -> hA
  hipLaunchKernelGGL((k_xform5<6>), dim3(XF_NB), dim3(256), 0, stream,
                     x, wl[0], bl[0], wrm[0], br[0], xlb, xrb);
  hipLaunchKernelGGL(k_fused, dim3(FUSE_NB), dim3(256), 0, stream,
                     xlb, xrb, rec, rp, order, wem[0], attv[0], bov[0], hA);
  // layer 2: hA -> hB
  hipLaunchKernelGGL((k_xform5<64>), dim3(XF_NB), dim3(256), 0, stream,
                     hA, wl[1], bl[1], wrm[1], br[1], xlb, xrb);
  hipLaunchKernelGGL(k_fused, dim3(FUSE_NB), dim3(256), 0, stream,
                     xlb, xrb, rec, rp, order, wem[1], attv[1], bov[1], hB);
  // layer 3: hB -> hA
  hipLaunchKernelGGL((k_xform5<64>), dim3(XF_NB), dim3(256), 0, stream,
                     hB, wl[2], bl[2], wrm[2], br[2], xlb, xrb);
  hipLaunchKernelGGL(k_fused, dim3(FUSE_NB), dim3(256), 0, stream,
                     xlb, xrb, rec, rp, order, wem[2], attv[2], bov[2], hA);
  // MLP head
  hipLaunchKernelGGL(k_mlp2, dim3((NN + 255) / 256), dim3(256), 0, stream,
                     hA, wlin, blin, wout, bout, outp);
}

// Round 19
// 516.441 us; speedup vs baseline: 1.0306x; 1.0306x over previous
//
#include <hip/hip_runtime.h>
#include <hip/hip_bf16.h>
#include <math.h>

#define NN 100000
#define NE 1600000
#define NEP 1700000        // NE + NN (self loops)
#define HD 64
#define NEGS 0.2f

typedef float f2 __attribute__((ext_vector_type(2)));
typedef float f4 __attribute__((ext_vector_type(4)));

__device__ __forceinline__ f2 sp2(float v) { return (f2){v, v}; }
__device__ __forceinline__ f4 sp4(float v) { return (f4){v, v, v, v}; }
__device__ __forceinline__ f2 ffma2(f2 a, f2 b, f2 c) {
#if __has_builtin(__builtin_elementwise_fma)
  return __builtin_elementwise_fma(a, b, c);
#else
  return a * b + c;
#endif
}
__device__ __forceinline__ f4 ffma4(f4 a, f4 b, f4 c) {
#if __has_builtin(__builtin_elementwise_fma)
  return __builtin_elementwise_fma(a, b, c);
#else
  return a * b + c;
#endif
}
__device__ __forceinline__ f2 fmax2(f2 a, f2 b) {
#if __has_builtin(__builtin_elementwise_max)
  return __builtin_elementwise_max(a, b);
#else
  f2 r; r.x = fmaxf(a.x, b.x); r.y = fmaxf(a.y, b.y); return r;
#endif
}
__device__ __forceinline__ f4 fmax4(f4 a, f4 b) {
#if __has_builtin(__builtin_elementwise_max)
  return __builtin_elementwise_max(a, b);
#else
  f4 r; r.x = fmaxf(a.x, b.x); r.y = fmaxf(a.y, b.y);
  r.z = fmaxf(a.z, b.z); r.w = fmaxf(a.w, b.w); return r;
#endif
}
// guaranteed v_readlane broadcast (never ds_bpermute); lane may be a
// runtime-uniform value, so partial unroll is safe (R11/R15 lesson).
__device__ __forceinline__ float rdlane(float v, int lane) {
  return __int_as_float(__builtin_amdgcn_readlane(__float_as_int(v), lane));
}

// ============================ CSR build ============================

__global__ void k_init_cnt(int* __restrict__ cnt, int* __restrict__ hist,
                           int* __restrict__ cursor2) {
  int i = blockIdx.x * 256 + threadIdx.x;
  if (i < NN) cnt[i] = 1;             // self loop pre-counted -> ranks start at 1
  if (blockIdx.x == 0) {
    if (threadIdx.x < 64) hist[threadIdx.x] = 0;
    else if (threadIdx.x < 128) cursor2[threadIdx.x - 64] = 0;
  }
}

// count in-degree AND record each edge's (temporary, nondeterministic) rank.
// rank >= 1; slot rp[dst]+0 is reserved for the self loop. The rank is only
// used for PLACEMENT; k_sortscat canonicalizes segment order afterwards.
__global__ void k_count_rank(const int* __restrict__ dst, int* __restrict__ cnt,
                             int* __restrict__ rank) {
  int base = (blockIdx.x * 256 + threadIdx.x) * 4;
  if (base >= NE) return;
  int4 dv = *(const int4*)(dst + base);
  int4 rv;
  rv.x = atomicAdd(&cnt[dv.x], 1);
  rv.y = atomicAdd(&cnt[dv.y], 1);
  rv.z = atomicAdd(&cnt[dv.z], 1);
  rv.w = atomicAdd(&cnt[dv.w], 1);
  *(int4*)(rank + base) = rv;
}

// scan of cnt -> rp (exclusive) ; also 64-bin degree histogram (LDS-batched)
__global__ void k_scan_a(const int* __restrict__ cnt, int* __restrict__ rp,
                         int* __restrict__ bsum, int* __restrict__ hist) {
  __shared__ int tmp[1024];
  __shared__ int lh[64];
  int t = threadIdx.x, b = blockIdx.x;
  int i = b * 1024 + t;
  int v = (i < NN) ? cnt[i] : 0;
  tmp[t] = v;
  if (t < 64) lh[t] = 0;
  __syncthreads();
  if (i < NN) atomicAdd(&lh[v < 63 ? v : 63], 1);
  for (int off = 1; off < 1024; off <<= 1) {
    int a = (t >= off) ? tmp[t - off] : 0;
    __syncthreads(); tmp[t] += a; __syncthreads();
  }
  if (i < NN) rp[i] = tmp[t] - v;     // exclusive
  if (t == 1023) bsum[b] = tmp[t];    // block total
  if (t < 64) { int h = lh[t]; if (h) atomicAdd(&hist[t], h); }
}

__global__ void k_scan_b(const int* __restrict__ bsum, int* __restrict__ boff, int nb,
                         const int* __restrict__ hist, int* __restrict__ cursor2) {
  __shared__ int tmp[1024];
  int t = threadIdx.x;
  int v = (t < nb) ? bsum[t] : 0;
  tmp[t] = v; __syncthreads();
  for (int off = 1; off < 1024; off <<= 1) {
    int a = (t >= off) ? tmp[t - off] : 0;
    __syncthreads(); tmp[t] += a; __syncthreads();
  }
  if (t < nb) boff[t] = tmp[t] - v;
  // exclusive scan of 64-bin degree histogram (wave 0 only) -> bin bases
  if (t < 64) {
    int h = hist[t];
    int s = h;
#pragma unroll
    for (int off = 1; off < 64; off <<= 1) {
      int u = __shfl_up(s, off);
      if (t >= off) s += u;
    }
    cursor2[t] = s - h;
  }
}

// finalize rp and scatter nodes into degree-bucketed order[].
// Hierarchical rank: LDS histogram -> one global atomic per (block,bin).
// order[] is a nondeterministic permutation WITHIN degree bins, but it only
// controls which nodes share a wave in k_fused — no node's math depends on it.
__global__ void k_scan_c(int* __restrict__ rp, const int* __restrict__ boff,
                         const int* __restrict__ deg,   // aliases cnt (degree)
                         int* __restrict__ cursor2, int* __restrict__ order) {
  __shared__ int lh[64];
  __shared__ int lbase[64];
  int t = threadIdx.x, b = blockIdx.x;
  int i = b * 1024 + t;
  if (t < 64) lh[t] = 0;
  __syncthreads();
  int bin = 0, lr = 0;
  if (i < NN) {
    int d = deg[i];
    bin = d < 63 ? d : 63;
    lr = atomicAdd(&lh[bin], 1);       // local rank within (block, bin)
    rp[i] = rp[i] + boff[b];
  }
  __syncthreads();
  if (t < 64) {
    int h = lh[t];
    lbase[t] = h ? atomicAdd(&cursor2[t], h) : 0;   // reserve range
  }
  __syncthreads();
  if (i < NN) order[lbase[bin] + lr] = i;
  if (i == 0) rp[NN] = NEP;
}

// ============ scatter edge IDs into segment slots (4B stores) ============
__global__ void __launch_bounds__(256) k_scatter_id(
    const int* __restrict__ dst, const int* __restrict__ rank,
    const int* __restrict__ rp, int* __restrict__ eid) {
  int base = (blockIdx.x * 256 + threadIdx.x) * 4;
  if (base >= NE) return;
  int4 dv = *(const int4*)(dst + base);
  int4 rv = *(const int4*)(rank + base);
  eid[rp[dv.x] + rv.x] = base + 0;
  eid[rp[dv.y] + rv.y] = base + 1;
  eid[rp[dv.z] + rv.z] = base + 2;
  eid[rp[dv.w] + rv.w] = base + 3;
}

// == canonicalize segment order (bitonic sort) + build records + self mean ==
// Wave per node: sort the <=64 edge ids ascending, gather src/ea, write the
// 32B records (coalesced), then butterfly-sum the attrs across the wave and
// lane 0 writes the self-loop mean record at slot rp[n]. All content is a
// deterministic function of inputs -> bitwise-identical output every call.
__global__ void __launch_bounds__(256) k_sortscat(
    const int* __restrict__ rp, int* __restrict__ eid,
    const int* __restrict__ src, const float* __restrict__ ea,
    float* __restrict__ rec) {
  int tid = threadIdx.x;
  int lane = tid & 63, wid = tid >> 6;
  int n = blockIdx.x * 4 + wid;
  if (n >= NN) return;
  int p0 = rp[n], p1 = rp[n + 1];
  int len = p1 - p0 - 1;               // number of real edges (slot p0 = self)
  if (len <= 0) {                      // isolated node: zero self record
    if (lane == 0) {
      float* r = rec + (size_t)p0 * 8;
      *(f4*)r       = (f4){__int_as_float(n), 0.f, 0.f, 0.f};
      *(f4*)(r + 4) = (f4){0.f, 0.f, 0.f, 0.f};
    }
    return;
  }
  f2 e01 = (f2){0, 0}, e23 = (f2){0, 0}, e45 = (f2){0, 0};
  if (len <= 64) {
    int v = (lane < len) ? eid[p0 + 1 + lane] : 0x7fffffff;
#pragma unroll
    for (int k = 2; k <= 64; k <<= 1) {
#pragma unroll
      for (int j = k >> 1; j > 0; j >>= 1) {
        int u = __shfl_xor(v, j);
        bool up = ((lane & k) == 0);
        bool lower = ((lane & j) == 0);
        int mn = v < u ? v : u;
        int mx = v < u ? u : v;
        v = (up == lower) ? mn : mx;
      }
    }
    if (lane < len) {
      int id = v;
      e01 = *(const f2*)(ea + (size_t)id * 6);
      e23 = *(const f2*)(ea + (size_t)id * 6 + 2);
      e45 = *(const f2*)(ea + (size_t)id * 6 + 4);
      int s = src[id];
      float* r = rec + (size_t)(p0 + 1 + lane) * 8;
      *(f4*)r       = (f4){__int_as_float(s), e01.x, e01.y, e23.x};
      *(f4*)(r + 4) = (f4){e23.y, e45.x, e45.y, 0.f};
    }
    // wave butterfly sum (idle lanes contribute 0) -> self-loop mean
    float s0 = e01.x, s1 = e01.y, s2 = e23.x, s3 = e23.y, s4 = e45.x, s5 = e45.y;
#pragma unroll
    for (int off = 1; off < 64; off <<= 1) {
      s0 += __shfl_xor(s0, off); s1 += __shfl_xor(s1, off);
      s2 += __shfl_xor(s2, off); s3 += __shfl_xor(s3, off);
      s4 += __shfl_xor(s4, off); s5 += __shfl_xor(s5, off);
    }
    if (lane == 0) {
      float inv = 1.0f / (float)len;
      float* r = rec + (size_t)p0 * 8;
      *(f4*)r       = (f4){__int_as_float(n), s0 * inv, s1 * inv, s2 * inv};
      *(f4*)(r + 4) = (f4){s3 * inv, s4 * inv, s5 * inv, 0.f};
    }
  } else {                              // deg > 64: ~impossible, serial path
    if (lane == 0) {
      for (int a = p0 + 2; a < p1; ++a) {
        int key = eid[a], b = a - 1;
        while (b > p0 && eid[b] > key) { eid[b + 1] = eid[b]; --b; }
        eid[b + 1] = key;
      }
      float s0 = 0, s1 = 0, s2 = 0, s3 = 0, s4 = 0, s5 = 0;
      for (int p = p0 + 1; p < p1; ++p) {
        int id = eid[p];
        f2 a01 = *(const f2*)(ea + (size_t)id * 6);
        f2 a23 = *(const f2*)(ea + (size_t)id * 6 + 2);
        f2 a45 = *(const f2*)(ea + (size_t)id * 6 + 4);
        s0 += a01.x; s1 += a01.y; s2 += a23.x;
        s3 += a23.y; s4 += a45.x; s5 += a45.y;
        float* r = rec + (size_t)p * 8;
        *(f4*)r       = (f4){__int_as_float(src[id]), a01.x, a01.y, a23.x};
        *(f4*)(r + 4) = (f4){a23.y, a45.x, a45.y, 0.f};
      }
      float inv = 1.0f / (float)len;
      float* r = rec + (size_t)p0 * 8;
      *(f4*)r       = (f4){__int_as_float(n), s0 * inv, s1 * inv, s2 * inv};
      *(f4*)(r + 4) = (f4){s3 * inv, s4 * inv, s5 * inv, 0.f};
    }
  }
}

// ====================== node transforms (xl, xr) ======================
// Wave handles 8 nodes, lane = channel. Weights in LDS packed 2-k per f4;
// per k-pair one ds_read_b128 + explicit v_readlane broadcasts (never
// ds_bpermute) + v_pk_fma_f32. Partial unroll batches 4 b128 loads.
template <int DIN>
__global__ void __launch_bounds__(256) k_xform5(
    const float* __restrict__ x,
    const float* __restrict__ wl, const float* __restrict__ bl,
    const float* __restrict__ wr, const float* __restrict__ br,
    float* __restrict__ xl, float* __restrict__ xr) {
  __shared__ f4 w_s[(DIN / 2) * 64];
  int tid = threadIdx.x;
  for (int idx = tid; idx < (DIN / 2) * 64; idx += 256) {
    int kk = idx >> 6, h2 = idx & 63;
    w_s[idx] = (f4){wl[(2 * kk) * 64 + h2],     wr[(2 * kk) * 64 + h2],
                    wl[(2 * kk + 1) * 64 + h2], wr[(2 * kk + 1) * 64 + h2]};
  }
  __syncthreads();
  int lane = tid & 63, wid = tid >> 6;
  int h = lane;
  f2 bpk = (f2){bl[h], br[h]};
  int n0 = (blockIdx.x * 4 + wid) * 8;       // 8 nodes per wave, exact fit
  float xv[8];
#pragma unroll
  for (int j = 0; j < 8; ++j)
    xv[j] = (lane < DIN) ? x[(size_t)(n0 + j) * DIN + lane] : 0.0f;
  f2 acc[8];
#pragma unroll
  for (int j = 0; j < 8; ++j) acc[j] = bpk;
#pragma unroll 4
  for (int kk = 0; kk < DIN / 2; ++kk) {
    f4 w = w_s[kk * 64 + h];
    f2 w0 = (f2){w.x, w.y};
    f2 w1 = (f2){w.z, w.w};
#pragma unroll
    for (int j = 0; j < 8; ++j) {
      float xk0 = rdlane(xv[j], 2 * kk);
      float xk1 = rdlane(xv[j], 2 * kk + 1);
      acc[j] = ffma2(sp2(xk0), w0, acc[j]);
      acc[j] = ffma2(sp2(xk1), w1, acc[j]);
    }
  }
#pragma unroll
  for (int j = 0; j < 8; ++j) {
    xl[(size_t)(n0 + j) * 64 + h] = acc[j].x;
    xr[(size_t)(n0 + j) * 64 + h] = acc[j].y;
  }
}

// ============== fused edge-logit + online softmax + aggregate ==============
// 16 lanes per node, 4 channels per lane (2x f2 for v_pk_fma_f32), 4 groups
// per wave. LPT: slots consumed in reverse degree order (heavy blocks first).
// Plain 2-edge loop (R16 form): measured best vs 4-edge unroll (R17) and
// SW pipeline (R18) — TLP already covers the rec-load latency.
__global__ void __launch_bounds__(256) k_fused(
    const float* __restrict__ xl, const float* __restrict__ xr,
    const float* __restrict__ rec,
    const int* __restrict__ rp, const int* __restrict__ order,
    const float* __restrict__ we, const float* __restrict__ att,
    const float* __restrict__ bo, float* __restrict__ hout) {
  int tid = threadIdx.x;
  int lane = tid & 63;
  int q = lane & 15;
  int c0 = q * 4;
  f2 w0a, w0b, w1a, w1b, w2a, w2b, w3a, w3b, w4a, w4b, w5a, w5b;
  w0a = *(const f2*)(we + 0 * 64 + c0); w0b = *(const f2*)(we + 0 * 64 + c0 + 2);
  w1a = *(const f2*)(we + 1 * 64 + c0); w1b = *(const f2*)(we + 1 * 64 + c0 + 2);
  w2a = *(const f2*)(we + 2 * 64 + c0); w2b = *(const f2*)(we + 2 * 64 + c0 + 2);
  w3a = *(const f2*)(we + 3 * 64 + c0); w3b = *(const f2*)(we + 3 * 64 + c0 + 2);
  w4a = *(const f2*)(we + 4 * 64 + c0); w4b = *(const f2*)(we + 4 * 64 + c0 + 2);
  w5a = *(const f2*)(we + 5 * 64 + c0); w5b = *(const f2*)(we + 5 * 64 + c0 + 2);
  f2 ata = *(const f2*)(att + c0) * 1.44269504f;       // fold log2(e)
  f2 atb = *(const f2*)(att + c0 + 2) * 1.44269504f;
  f2 boa = *(const f2*)(bo + c0);
  f2 bob = *(const f2*)(bo + c0 + 2);
  int gw = (blockIdx.x * 256 + tid) >> 6;       // global wave id
  int slot = gw * 4 + (lane >> 4);              // node slot for this group
  int n = (slot < NN) ? order[NN - 1 - slot] : -1;   // LPT: heavy first
  int p0 = 0, p1 = 0;
  f2 xra = (f2){0, 0}, xrb2 = (f2){0, 0};
  if (n >= 0) {
    p0 = rp[n]; p1 = rp[n + 1];
    const f4 t = *(const f4*)(xr + (size_t)n * 64 + c0);
    xra = (f2){t.x, t.y}; xrb2 = (f2){t.z, t.w};
  }
  float m = -INFINITY, den = 0.0f;
  f2 acca = (f2){0, 0}, accb = (f2){0, 0};
  int p = p0;
  for (; p + 2 <= p1; p += 2) {
    const f4* ra = (const f4*)(rec + (size_t)p * 8);
    f4 qa0 = ra[0], qa1 = ra[1], qb0 = ra[2], qb1 = ra[3];
    int sA = __float_as_int(qa0.x), sB = __float_as_int(qb0.x);
    f4 xA = *(const f4*)(xl + (size_t)sA * 64 + c0);
    f4 xB = *(const f4*)(xl + (size_t)sB * 64 + c0);
    f2 xAa = (f2){xA.x, xA.y}, xAb = (f2){xA.z, xA.w};
    f2 xBa = (f2){xB.x, xB.y}, xBb = (f2){xB.z, xB.w};
    // edge A logit (packed pairs)
    f2 tA = xAa + xra;
    tA = ffma2(sp2(qa0.y), w0a, tA); tA = ffma2(sp2(qa0.z), w1a, tA);
    tA = ffma2(sp2(qa0.w), w2a, tA); tA = ffma2(sp2(qa1.x), w3a, tA);
    tA = ffma2(sp2(qa1.y), w4a, tA); tA = ffma2(sp2(qa1.z), w5a, tA);
    f2 pav = fmax2(tA, sp2(0.2f) * tA) * ata;
    f2 uA = xAb + xrb2;
    uA = ffma2(sp2(qa0.y), w0b, uA); uA = ffma2(sp2(qa0.z), w1b, uA);
    uA = ffma2(sp2(qa0.w), w2b, uA); uA = ffma2(sp2(qa1.x), w3b, uA);
    uA = ffma2(sp2(qa1.y), w4b, uA); uA = ffma2(sp2(qa1.z), w5b, uA);
    pav = ffma2(fmax2(uA, sp2(0.2f) * uA), atb, pav);
    // edge B logit
    f2 tB = xBa + xra;
    tB = ffma2(sp2(qb0.y), w0a, tB); tB = ffma2(sp2(qb0.z), w1a, tB);
    tB = ffma2(sp2(qb0.w), w2a, tB); tB = ffma2(sp2(qb1.x), w3a, tB);
    tB = ffma2(sp2(qb1.y), w4a, tB); tB = ffma2(sp2(qb1.z), w5a, tB);
    f2 pbv = fmax2(tB, sp2(0.2f) * tB) * ata;
    f2 uB = xBb + xrb2;
    uB = ffma2(sp2(qb0.y), w0b, uB); uB = ffma2(sp2(qb0.z), w1b, uB);
    uB = ffma2(sp2(qb0.w), w2b, uB); uB = ffma2(sp2(qb1.x), w3b, uB);
    uB = ffma2(sp2(qb1.y), w4b, uB); uB = ffma2(sp2(qb1.z), w5b, uB);
    pbv = ffma2(fmax2(uB, sp2(0.2f) * uB), atb, pbv);
    float pa = pav.x + pav.y;
    float pb = pbv.x + pbv.y;
    pa += __shfl_xor(pa, 1); pb += __shfl_xor(pb, 1);
    pa += __shfl_xor(pa, 2); pb += __shfl_xor(pb, 2);
    pa += __shfl_xor(pa, 4); pb += __shfl_xor(pb, 4);
    pa += __shfl_xor(pa, 8); pb += __shfl_xor(pb, 8);
    float nm = fmaxf(m, fmaxf(pa, pb));
    float sc = exp2f(m - nm);                 // first iter: exp2(-inf)=0
    float eA = exp2f(pa - nm);
    float eB = exp2f(pb - nm);
    m = nm;
    den = fmaf(den, sc, eA + eB);
    acca = ffma2(acca, sp2(sc), ffma2(sp2(eA), xAa, sp2(eB) * xBa));
    accb = ffma2(accb, sp2(sc), ffma2(sp2(eA), xAb, sp2(eB) * xBb));
  }
  if (p < p1) {                                  // tail edge
    const f4* ra = (const f4*)(rec + (size_t)p * 8);
    f4 r0 = ra[0], r1 = ra[1];
    int s = __float_as_int(r0.x);
    f4 xt = *(const f4*)(xl + (size_t)s * 64 + c0);
    f2 xa = (f2){xt.x, xt.y}, xb = (f2){xt.z, xt.w};
    f2 t = xa + xra;
    t = ffma2(sp2(r0.y), w0a, t); t = ffma2(sp2(r0.z), w1a, t);
    t = ffma2(sp2(r0.w), w2a, t); t = ffma2(sp2(r1.x), w3a, t);
    t = ffma2(sp2(r1.y), w4a, t); t = ffma2(sp2(r1.z), w5a, t);
    f2 pv = fmax2(t, sp2(0.2f) * t) * ata;
    f2 u = xb + xrb2;
    u = ffma2(sp2(r0.y), w0b, u); u = ffma2(sp2(r0.z), w1b, u);
    u = ffma2(sp2(r0.w), w2b, u); u = ffma2(sp2(r1.x), w3b, u);
    u = ffma2(sp2(r1.y), w4b, u); u = ffma2(sp2(r1.z), w5b, u);
    pv = ffma2(fmax2(u, sp2(0.2f) * u), atb, pv);
    float part = pv.x + pv.y;
    part += __shfl_xor(part, 1);
    part += __shfl_xor(part, 2);
    part += __shfl_xor(part, 4);
    part += __shfl_xor(part, 8);
    float nm = fmaxf(m, part);
    float sc = exp2f(m - nm);
    float ex = exp2f(part - nm);
    m = nm;
    den = fmaf(den, sc, ex);
    acca = ffma2(acca, sp2(sc), sp2(ex) * xa);
    accb = ffma2(accb, sp2(sc), sp2(ex) * xb);
  }
  if (n >= 0) {
    float inv = 1.0f / (den + 1e-16f);
    f2 oa = ffma2(acca, sp2(inv), boa);
    f2 ob = ffma2(accb, sp2(inv), bob);
    oa = fmax2(oa, (f2){0, 0});
    ob = fmax2(ob, (f2){0, 0});
    f4 o = (f4){oa.x, oa.y, ob.x, ob.y};
    *(f4*)(hout + (size_t)n * 64 + c0) = o;
  }
}

// ====================== MLP head: 64 -> 32 (relu) -> 4 ======================
// Thread-per-node; weights broadcast from LDS; 8 independent f4 acc chains.
__global__ void __launch_bounds__(256) k_mlp2(
    const float* __restrict__ hin,
    const float* __restrict__ wlin, const float* __restrict__ blin,
    const float* __restrict__ wout, const float* __restrict__ bout,
    float* __restrict__ out) {
  __shared__ float wl_s[64 * 32];
  __shared__ float bl_s[32];
  __shared__ float wo_s[32 * 4];
  __shared__ float bo_s[4];
  int tid = threadIdx.x;
#pragma unroll
  for (int i = 0; i < 8; ++i) wl_s[tid + i * 256] = wlin[tid + i * 256];
  if (tid < 128) wo_s[tid] = wout[tid];
  if (tid < 32) bl_s[tid] = blin[tid];
  if (tid >= 32 && tid < 36) bo_s[tid - 32] = bout[tid - 32];
  __syncthreads();
  int n = blockIdx.x * 256 + tid;
  if (n >= NN) return;
  const f4* hp = (const f4*)(hin + (size_t)n * 64);
  f4 h[16];
#pragma unroll
  for (int i = 0; i < 16; ++i) h[i] = hp[i];
  f4 acc[8];
#pragma unroll
  for (int j4 = 0; j4 < 8; ++j4) acc[j4] = *(const f4*)(bl_s + j4 * 4);
#pragma unroll
  for (int k = 0; k < 64; ++k) {
    float hk = ((const float*)h)[k];
    const f4* wrow = (const f4*)(wl_s + k * 32);
#pragma unroll
    for (int j4 = 0; j4 < 8; ++j4)
      acc[j4] = ffma4(sp4(hk), wrow[j4], acc[j4]);
  }
  f4 o4 = *(const f4*)(bo_s);
#pragma unroll
  for (int j4 = 0; j4 < 8; ++j4) {
    f4 hid = fmax4(acc[j4], sp4(0.0f));
    const f4* wo = (const f4*)(wo_s + j4 * 16);
    o4 = ffma4(sp4(hid.x), wo[0], o4);
    o4 = ffma4(sp4(hid.y), wo[1], o4);
    o4 = ffma4(sp4(hid.z), wo[2], o4);
    o4 = ffma4(sp4(hid.w), wo[3], o4);
  }
  *(f4*)(out + (size_t)n * 4) = o4;
}

// ============================ launch ============================

extern "C" void kernel_launch(void* const* d_in, const int* in_sizes, int n_in,
                              void* d_out, int out_size, void* d_ws, size_t ws_size,
                              hipStream_t stream) {
  const float* x  = (const float*)d_in[0];
  const int*   ei = (const int*)d_in[1];
  const float* ea = (const float*)d_in[2];
  const int* src = ei;
  const int* dst = ei + NE;

  const float *wl[3], *bl[3], *wrm[3], *br[3], *wem[3], *attv[3], *bov[3];
  for (int l = 0; l < 3; ++l) {
    int b = 3 + l * 7;
    wl[l]  = (const float*)d_in[b + 0];
    bl[l]  = (const float*)d_in[b + 1];
    wrm[l] = (const float*)d_in[b + 2];
    br[l]  = (const float*)d_in[b + 3];
    wem[l] = (const float*)d_in[b + 4];
    attv[l]= (const float*)d_in[b + 5];
    bov[l] = (const float*)d_in[b + 6];
  }
  const float* wlin = (const float*)d_in[24];
  const float* blin = (const float*)d_in[25];
  const float* wout = (const float*)d_in[26];
  const float* bout = (const float*)d_in[27];
  float* outp = (float*)d_out;

  // workspace carve (256B aligned)
  char* w = (char*)d_ws;
  size_t off = 0;
  auto carve = [&](size_t bytes) -> void* {
    void* p = w + off;
    off += (bytes + 255) & ~(size_t)255;
    return p;
  };
  int*   cnt  = (int*)carve((size_t)NN * 4);
  int*   rp   = (int*)carve((size_t)(NN + 1) * 4);
  int*   bsum = (int*)carve(1024 * 4);
  int*   boff = (int*)carve(1024 * 4);
  int*   hist = (int*)carve(64 * 4);
  int*   cur2 = (int*)carve(64 * 4);
  int*   order= (int*)carve((size_t)NN * 4);
  int*   rank = (int*)carve((size_t)NE * 4);
  int*   eid  = (int*)carve((size_t)NEP * 4);
  float* rec  = (float*)carve((size_t)NEP * 32);      // 32B records
  float* xlb  = (float*)carve((size_t)NN * 64 * 4);
  float* xrb  = (float*)carve((size_t)NN * 64 * 4);
  float* hA   = (float*)carve((size_t)NN * 64 * 4);
  float* hB   = (float*)carve((size_t)NN * 64 * 4);
  (void)ws_size; (void)n_in; (void)in_sizes; (void)out_size;

  const int SCAN_NB = (NN + 1023) / 1024;  // 98
  const int FUSE_NB = (NN + 15) / 16;      // 6250 blocks: 4 waves x 4 groups each
  const int CR_NB   = (NE / 4 + 255) / 256;
  const int XF_NB   = NN / 32;             // 3125 blocks, 8 nodes/wave, exact
  const int SS_NB   = (NN + 3) / 4;        // sortscat: wave per node

  hipLaunchKernelGGL(k_init_cnt, dim3((NN + 255) / 256), dim3(256), 0, stream,
                     cnt, hist, cur2);
  hipLaunchKernelGGL(k_count_rank, dim3(CR_NB), dim3(256), 0, stream, dst, cnt, rank);
  hipLaunchKernelGGL(k_scan_a, dim3(SCAN_NB), dim3(1024), 0, stream, cnt, rp, bsum, hist);
  hipLaunchKernelGGL(k_scan_b, dim3(1), dim3(1024), 0, stream, bsum, boff, SCAN_NB,
                     hist, cur2);
  hipLaunchKernelGGL(k_scan_c, dim3(SCAN_NB), dim3(1024), 0, stream, rp, boff, cnt,
                     cur2, order);
  hipLaunchKernelGGL(k_scatter_id, dim3(CR_NB), dim3(256), 0, stream,
                     dst, rank, rp, eid);
  hipLaunchKernelGGL(k_sortscat, dim3(SS_NB), dim3(256), 0, stream,
                     rp, eid, src, ea, rec);

  // layer 1 (din=6): x -> hA
  hipLaunchKernelGGL((k_xform5<6>), dim3(XF_NB), dim3(256), 0, stream,
                     x, wl[0], bl[0], wrm[0], br[0], xlb, xrb);
  hipLaunchKernelGGL(k_fused, dim3(FUSE_NB), dim3(256), 0, stream,
                     xlb, xrb, rec, rp, order, wem[0], attv[0], bov[0], hA);
  // layer 2: hA -> hB
  hipLaunchKernelGGL((k_xform5<64>), dim3(XF_NB), dim3(256), 0, stream,
                     hA, wl[1], bl[1], wrm[1], br[1], xlb, xrb);
  hipLaunchKernelGGL(k_fused, dim3(FUSE_NB), dim3(256), 0, stream,
                     xlb, xrb, rec, rp, order, wem[1], attv[1], bov[1], hB);
  // layer 3: hB -> hA
  hipLaunchKernelGGL((k_xform5<64>), dim3(XF_NB), dim3(256), 0, stream,
                     hB, wl[2], bl[2], wrm[2], br[2], xlb, xrb);
  hipLaunchKernelGGL(k_fused, dim3(FUSE_NB), dim3(256), 0, stream,
                     xlb, xrb, rec, rp, order, wem[2], attv[2], bov[2], hA);
  // MLP head
  hipLaunchKernelGGL(k_mlp2, dim3((NN + 255) / 256), dim3(256), 0, stream,
                     hA, wlin, blin, wout, bout, outp);
}